// Round 27
// baseline (610.030 us; speedup 1.0000x reference)
//
#include <hip/hip_runtime.h>
#include <cstdint>
#include <cstddef>

#define BROWS 32768
#define NEXP 8
#define CAP 10240          // per-expert row capacity (E[count]=8192, std~78)
#define CAPBLK (CAP / 64)
#define NBLKC (CAPBLK * NEXP)

typedef short bf16x8 __attribute__((ext_vector_type(8)));
typedef float f32x4 __attribute__((ext_vector_type(4)));
typedef float f32x2 __attribute__((ext_vector_type(2)));

__device__ __forceinline__ unsigned short f2b(float f) {
  union { float f; unsigned u; } v; v.f = f;
  unsigned r = (v.u + 0x7fffu + ((v.u >> 16) & 1u)) >> 16;
  return (unsigned short)r;
}
__device__ __forceinline__ float b2f(unsigned short s) {
  union { unsigned u; float f; } v; v.u = ((unsigned)s) << 16; return v.f;
}
__device__ __forceinline__ float fast_elu(float x) {
  return x > 0.f ? x : __expf(x) - 1.f;
}

// ---------------- gate GEMM body (packed fp32; RAW => store partials) ----------------
// ktb/ntk select a K-slice (kt tiles). RAW skips bias/ELU (split-K partial).
template<bool TWOSRC, bool RAW>
__device__ __forceinline__ void gate_gemm_body(
    char* ldsraw, int rb, int nb, int ktb, int ntk,
    const float* __restrict__ A0, int As0,
    const float* __restrict__ A1, int As1, int Ks,
    const float* __restrict__ W, const float* __restrict__ bias,
    int N, float* __restrict__ Out) {
  float (*At)[132] = (float(*)[132])ldsraw;
  float (*Bs)[132] = (float(*)[132])(ldsraw + 32 * 132 * 4);

  int tid = threadIdx.x;
  int tx = tid & 15, tyg = tid >> 4;
  int arow = tid >> 1, aq = (tid & 1) * 16;
  int brow = tid >> 3, bc = (tid & 7) * 16;

  f32x2 acc[8][4] = {};

  float4 a0, a1, a2, a3, b0, b1, b2, b3;
  {
    int ka = ktb * 32 + aq;
    const float* arp = (!TWOSRC || ka < Ks)
        ? (A0 + (size_t)(rb + arow) * As0 + ka)
        : (A1 + (size_t)(rb + arow) * As1 + (ka - Ks));
    a0 = *(const float4*)(arp);
    a1 = *(const float4*)(arp + 4);
    a2 = *(const float4*)(arp + 8);
    a3 = *(const float4*)(arp + 12);
    const float* brp = W + (size_t)(ktb * 32 + brow) * N + nb + bc;
    b0 = *(const float4*)(brp);
    b1 = *(const float4*)(brp + 4);
    b2 = *(const float4*)(brp + 8);
    b3 = *(const float4*)(brp + 12);
  }

  const int ke = ktb + ntk;
  for (int kt = ktb; kt < ke; ++kt) {
    __syncthreads();
    At[aq + 0][arow] = a0.x;  At[aq + 1][arow] = a0.y;
    At[aq + 2][arow] = a0.z;  At[aq + 3][arow] = a0.w;
    At[aq + 4][arow] = a1.x;  At[aq + 5][arow] = a1.y;
    At[aq + 6][arow] = a1.z;  At[aq + 7][arow] = a1.w;
    At[aq + 8][arow] = a2.x;  At[aq + 9][arow] = a2.y;
    At[aq + 10][arow] = a2.z; At[aq + 11][arow] = a2.w;
    At[aq + 12][arow] = a3.x; At[aq + 13][arow] = a3.y;
    At[aq + 14][arow] = a3.z; At[aq + 15][arow] = a3.w;
    *(float4*)(&Bs[brow][bc])      = b0;
    *(float4*)(&Bs[brow][bc + 4])  = b1;
    *(float4*)(&Bs[brow][bc + 8])  = b2;
    *(float4*)(&Bs[brow][bc + 12]) = b3;
    __syncthreads();

    if (kt + 1 < ke) {
      int ka = (kt + 1) * 32 + aq;
      const float* arp = (!TWOSRC || ka < Ks)
          ? (A0 + (size_t)(rb + arow) * As0 + ka)
          : (A1 + (size_t)(rb + arow) * As1 + (ka - Ks));
      a0 = *(const float4*)(arp);
      a1 = *(const float4*)(arp + 4);
      a2 = *(const float4*)(arp + 8);
      a3 = *(const float4*)(arp + 12);
      const float* brp = W + (size_t)((kt + 1) * 32 + brow) * N + nb + bc;
      b0 = *(const float4*)(brp);
      b1 = *(const float4*)(brp + 4);
      b2 = *(const float4*)(brp + 8);
      b3 = *(const float4*)(brp + 12);
    }

#pragma unroll 4
    for (int kk = 0; kk < 32; ++kk) {
      float4 av0 = *(const float4*)(&At[kk][tyg * 8]);
      float4 av1 = *(const float4*)(&At[kk][tyg * 8 + 4]);
      float4 bq0 = *(const float4*)(&Bs[kk][tx * 8]);
      float4 bq1 = *(const float4*)(&Bs[kk][tx * 8 + 4]);
      f32x2 bp0 = {bq0.x, bq0.y}, bp1 = {bq0.z, bq0.w};
      f32x2 bp2 = {bq1.x, bq1.y}, bp3 = {bq1.z, bq1.w};
      float av[8] = {av0.x, av0.y, av0.z, av0.w, av1.x, av1.y, av1.z, av1.w};
#pragma unroll
      for (int i = 0; i < 8; ++i) {
        f32x2 as = {av[i], av[i]};
        acc[i][0] = __builtin_elementwise_fma(as, bp0, acc[i][0]);
        acc[i][1] = __builtin_elementwise_fma(as, bp1, acc[i][1]);
        acc[i][2] = __builtin_elementwise_fma(as, bp2, acc[i][2]);
        acc[i][3] = __builtin_elementwise_fma(as, bp3, acc[i][3]);
      }
    }
  }

  if (RAW) {
#pragma unroll
    for (int i = 0; i < 8; ++i) {
      size_t orow = (size_t)(rb + tyg * 8 + i) * N + nb + tx * 8;
      float4 w0; w0.x = acc[i][0][0]; w0.y = acc[i][0][1];
      w0.z = acc[i][1][0]; w0.w = acc[i][1][1];
      float4 w1; w1.x = acc[i][2][0]; w1.y = acc[i][2][1];
      w1.z = acc[i][3][0]; w1.w = acc[i][3][1];
      *(float4*)(&Out[orow]) = w0;
      *(float4*)(&Out[orow + 4]) = w1;
    }
    return;
  }

  float4 bia0 = *(const float4*)(&bias[nb + tx * 8]);
  float4 bia1 = *(const float4*)(&bias[nb + tx * 8 + 4]);
  float bia[8] = {bia0.x, bia0.y, bia0.z, bia0.w, bia1.x, bia1.y, bia1.z, bia1.w};

#pragma unroll
  for (int i = 0; i < 8; ++i) {
    float o[8];
#pragma unroll
    for (int j = 0; j < 4; ++j) {
      o[2 * j]     = acc[i][j][0] + bia[2 * j];
      o[2 * j + 1] = acc[i][j][1] + bia[2 * j + 1];
    }
#pragma unroll
    for (int j = 0; j < 8; ++j) o[j] = (o[j] > 0.f) ? o[j] : expm1f(o[j]);
    size_t orow = (size_t)(rb + tyg * 8 + i) * N + nb + tx * 8;
    float4 w0; w0.x = o[0]; w0.y = o[1]; w0.z = o[2]; w0.w = o[3];
    float4 w1; w1.x = o[4]; w1.y = o[5]; w1.z = o[6]; w1.w = o[7];
    *(float4*)(&Out[orow]) = w0;
    *(float4*)(&Out[orow + 4]) = w1;
  }
}

// ---------------- k_front: split-K gate1 + weight transposes + converts ----------------
// Gate1: 1024 blocks (256 rb x 2 nb x 2 K-slices) writing raw partials (r20 form,
// measured 197us) -> 4/CU gate occupancy. Combine moved to standalone k_comb.
__launch_bounds__(256, 4)
__global__ void k_front(const float* __restrict__ state, const float* __restrict__ vlm,
                        unsigned short* __restrict__ st_bf, unsigned short* __restrict__ vl_bf,
                        int* __restrict__ cntaux,
                        const float* __restrict__ gw1,
                        float* __restrict__ gh1a, float* __restrict__ gh1b,
                        const float* __restrict__ s1w, unsigned short* __restrict__ s1d,
                        const float* __restrict__ s2w, unsigned short* __restrict__ s2d,
                        const float* __restrict__ v1w, unsigned short* __restrict__ v1d,
                        const float* __restrict__ v2w, unsigned short* __restrict__ v2d,
                        const float* __restrict__ f1w, unsigned short* __restrict__ f1d,
                        const float* __restrict__ f2w, unsigned short* __restrict__ f2d) {
  __shared__ char lds[2 * 32 * 132 * 4];   // 33792 B (gate path); wtrans uses prefix
  int bid = blockIdx.x, tid = threadIdx.x;

  if (bid < 1024) {
    int rb = (bid & 255) * 128;
    int nb = ((bid >> 8) & 1) * 128;
    int z  = bid >> 9;
    if (z == 0)
      gate_gemm_body<true, true>(lds, rb, nb, 0, 10, state, 96, vlm, 512, 96,
                                 gw1, nullptr, 256, gh1a);
    else
      gate_gemm_body<true, true>(lds, rb, nb, 10, 9, state, 96, vlm, 512, 96,
                                 gw1, nullptr, 256, gh1b);
  } else if (bid < 1024 + 6144) {
    float (*tile)[33] = (float(*)[33])lds;
    int b2 = bid - 1024;
    int e = b2 / 768, r = b2 % 768;
    const float* src; unsigned short* dst; int K, N, Kpad, nbx;
    if (r < 32)       { src = s1w; dst = s1d; K = 96;  N = 256; Kpad = 128; nbx = 4;  }
    else if (r < 64)  { src = s2w; dst = s2d; K = 256; N = 128; Kpad = 256; nbx = 8;  r -= 32;  }
    else if (r < 320) { src = v1w; dst = v1d; K = 512; N = 512; Kpad = 512; nbx = 16; r -= 64;  }
    else if (r < 448) { src = v2w; dst = v2d; K = 512; N = 256; Kpad = 512; nbx = 16; r -= 320; }
    else if (r < 640) { src = f1w; dst = f1d; K = 384; N = 512; Kpad = 384; nbx = 12; r -= 448; }
    else              { src = f2w; dst = f2d; K = 512; N = 256; Kpad = 512; nbx = 16; r -= 640; }
    int k0 = (r % nbx) * 32, n0 = (r / nbx) * 32;
    int tx = tid & 31, ty = tid >> 5;   // 32 x 8
    for (int i = 0; i < 32; i += 8) {
      int k = k0 + ty + i;
      tile[ty + i][tx] = (k < K) ? src[((size_t)e * K + k) * N + n0 + tx] : 0.f;
    }
    __syncthreads();
    for (int i = 0; i < 32; i += 8) {
      int n = n0 + ty + i;
      dst[((size_t)e * N + n) * Kpad + k0 + tx] = f2b(tile[tx][ty + i]);
    }
  } else {
    int cid = bid - (1024 + 6144);
    if (cid == 0 && tid < 64) cntaux[tid] = 0;
    const int NB1 = (BROWS * 128) / 256;
    if (cid < NB1) {
      int i = cid * 256 + tid;
      int r = i >> 7, c = i & 127;
      st_bf[i] = f2b(c < 96 ? state[(size_t)r * 96 + c] : 0.f);
    } else {
      int i = (cid - NB1) * 256 + tid;
      vl_bf[i] = f2b(vlm[i]);
    }
  }
}

// ------- k_comb: gh1 = elu(gh1a + gh1b + gb1), pure streaming (split-K combine) -------
__global__ void k_comb(const float* __restrict__ a, const float* __restrict__ b,
                       const float* __restrict__ gb1, float* __restrict__ out) {
  int i = (blockIdx.x * 256 + threadIdx.x) * 8;
  int col = i & 255;
  float4 x0 = *(const float4*)(&a[i]);
  float4 x1 = *(const float4*)(&a[i + 4]);
  float4 y0 = *(const float4*)(&b[i]);
  float4 y1 = *(const float4*)(&b[i + 4]);
  float4 c0 = *(const float4*)(&gb1[col]);
  float4 c1 = *(const float4*)(&gb1[col + 4]);
  float o[8];
  o[0] = x0.x + y0.x + c0.x; o[1] = x0.y + y0.y + c0.y;
  o[2] = x0.z + y0.z + c0.z; o[3] = x0.w + y0.w + c0.w;
  o[4] = x1.x + y1.x + c1.x; o[5] = x1.y + y1.y + c1.y;
  o[6] = x1.z + y1.z + c1.z; o[7] = x1.w + y1.w + c1.w;
#pragma unroll
  for (int j = 0; j < 8; ++j) o[j] = (o[j] > 0.f) ? o[j] : expm1f(o[j]);
  float4 w0; w0.x = o[0]; w0.y = o[1]; w0.z = o[2]; w0.w = o[3];
  float4 w1; w1.x = o[4]; w1.y = o[5]; w1.z = o[6]; w1.w = o[7];
  *(float4*)(&out[i]) = w0;
  *(float4*)(&out[i + 4]) = w1;
}

// ------- merged gate tail: gate2 GEMM (128 rows/block) + logits/top2 in-block -------
#define ACTION_SZ (32768 * 12)
#define AUX_OFF   ACTION_SZ
#define IDX_OFF   (ACTION_SZ + 1)
#define SCO_OFF   (ACTION_SZ + 1 + 32768 * 2)

__launch_bounds__(256, 2)
__global__ void k_gtail(const float* __restrict__ gh1,
                        const float* __restrict__ gw2, const float* __restrict__ gb2,
                        const float* __restrict__ gw3, const float* __restrict__ gb3,
                        float* __restrict__ out, float* __restrict__ aux,
                        int* __restrict__ bcnt, float* __restrict__ selbuf) {
  __shared__ char lds[71680];
  float (*At)[132] = (float(*)[132])lds;
  float (*Bs)[132] = (float(*)[132])(lds + 32 * 132 * 4);
  float (*ghT)[132] = (float(*)[132])lds;        // phase 2: [col 0..127][row 0..127]
  float* gw3s = (float*)(lds + 67584);           // 128*8 floats (4KB)
  __shared__ float sprob[8];

  int tid = threadIdx.x;
  int rb = blockIdx.x * 128;
  int tx = tid & 15, tyg = tid >> 4;
  int arow = tid >> 1, aq = (tid & 1) * 16;
  int brow = tid >> 3, bc = (tid & 7) * 16;
  const int N = 128, K = 256;

  f32x2 acc[8][4] = {};
  float4 a0, a1, a2, a3, b0, b1, b2, b3;
  {
    const float* arp = gh1 + (size_t)(rb + arow) * 256 + aq;
    a0 = *(const float4*)(arp);
    a1 = *(const float4*)(arp + 4);
    a2 = *(const float4*)(arp + 8);
    a3 = *(const float4*)(arp + 12);
    const float* brp = gw2 + (size_t)brow * N + bc;
    b0 = *(const float4*)(brp);
    b1 = *(const float4*)(brp + 4);
    b2 = *(const float4*)(brp + 8);
    b3 = *(const float4*)(brp + 12);
  }
  const int NT = K / 32;
  for (int kt = 0; kt < NT; ++kt) {
    __syncthreads();
    At[aq + 0][arow] = a0.x;  At[aq + 1][arow] = a0.y;
    At[aq + 2][arow] = a0.z;  At[aq + 3][arow] = a0.w;
    At[aq + 4][arow] = a1.x;  At[aq + 5][arow] = a1.y;
    At[aq + 6][arow] = a1.z;  At[aq + 7][arow] = a1.w;
    At[aq + 8][arow] = a2.x;  At[aq + 9][arow] = a2.y;
    At[aq + 10][arow] = a2.z; At[aq + 11][arow] = a2.w;
    At[aq + 12][arow] = a3.x; At[aq + 13][arow] = a3.y;
    At[aq + 14][arow] = a3.z; At[aq + 15][arow] = a3.w;
    *(float4*)(&Bs[brow][bc])      = b0;
    *(float4*)(&Bs[brow][bc + 4])  = b1;
    *(float4*)(&Bs[brow][bc + 8])  = b2;
    *(float4*)(&Bs[brow][bc + 12]) = b3;
    __syncthreads();

    if (kt + 1 < NT) {
      int ka = (kt + 1) * 32 + aq;
      const float* arp = gh1 + (size_t)(rb + arow) * 256 + ka;
      a0 = *(const float4*)(arp);
      a1 = *(const float4*)(arp + 4);
      a2 = *(const float4*)(arp + 8);
      a3 = *(const float4*)(arp + 12);
      const float* brp = gw2 + (size_t)((kt + 1) * 32 + brow) * N + bc;
      b0 = *(const float4*)(brp);
      b1 = *(const float4*)(brp + 4);
      b2 = *(const float4*)(brp + 8);
      b3 = *(const float4*)(brp + 12);
    }

#pragma unroll 4
    for (int kk = 0; kk < 32; ++kk) {
      float4 av0 = *(const float4*)(&At[kk][tyg * 8]);
      float4 av1 = *(const float4*)(&At[kk][tyg * 8 + 4]);
      float4 bq0 = *(const float4*)(&Bs[kk][tx * 8]);
      float4 bq1 = *(const float4*)(&Bs[kk][tx * 8 + 4]);
      f32x2 bp0 = {bq0.x, bq0.y}, bp1 = {bq0.z, bq0.w};
      f32x2 bp2 = {bq1.x, bq1.y}, bp3 = {bq1.z, bq1.w};
      float av[8] = {av0.x, av0.y, av0.z, av0.w, av1.x, av1.y, av1.z, av1.w};
#pragma unroll
      for (int i = 0; i < 8; ++i) {
        f32x2 as = {av[i], av[i]};
        acc[i][0] = __builtin_elementwise_fma(as, bp0, acc[i][0]);
        acc[i][1] = __builtin_elementwise_fma(as, bp1, acc[i][1]);
        acc[i][2] = __builtin_elementwise_fma(as, bp2, acc[i][2]);
        acc[i][3] = __builtin_elementwise_fma(as, bp3, acc[i][3]);
      }
    }
  }

  float4 bia0 = *(const float4*)(&gb2[tx * 8]);
  float4 bia1 = *(const float4*)(&gb2[tx * 8 + 4]);
  float bia[8] = {bia0.x, bia0.y, bia0.z, bia0.w, bia1.x, bia1.y, bia1.z, bia1.w};

  __syncthreads();
  if (tid < 8) sprob[tid] = 0.f;
#pragma unroll
  for (int i = 0; i < 8; ++i) {
    int lr = tyg * 8 + i;
#pragma unroll
    for (int j = 0; j < 4; ++j) {
      float o0 = acc[i][j][0] + bia[2 * j];
      float o1 = acc[i][j][1] + bia[2 * j + 1];
      o0 = (o0 > 0.f) ? o0 : expm1f(o0);
      o1 = (o1 > 0.f) ? o1 : expm1f(o1);
      ghT[tx * 8 + 2 * j][lr] = o0;
      ghT[tx * 8 + 2 * j + 1][lr] = o1;
    }
  }
  for (int i = tid; i < 128 * 8; i += 256) gw3s[i] = gw3[i];
  __syncthreads();

  if (tid < 128) {
    int b = rb + tid;
    int lane = tid & 63, w = tid >> 6;
    float lg[8];
#pragma unroll
    for (int j = 0; j < 8; ++j) lg[j] = gb3[j];
    for (int k = 0; k < 128; ++k) {
      float h = ghT[k][tid];
#pragma unroll
      for (int j = 0; j < 8; ++j) lg[j] += h * gw3s[k * 8 + j];
    }
    float m = lg[0];
#pragma unroll
    for (int j = 1; j < 8; ++j) m = fmaxf(m, lg[j]);
    float probs[8], sum = 0.f;
#pragma unroll
    for (int j = 0; j < 8; ++j) { float p = expf(lg[j] - m); probs[j] = p; sum += p; }
    float inv = 1.f / sum;
#pragma unroll
    for (int j = 0; j < 8; ++j) probs[j] *= inv;
    int i0 = 0, i1;
    float v0 = -1e30f;
#pragma unroll
    for (int j = 0; j < 8; ++j) if (probs[j] > v0) { v0 = probs[j]; i0 = j; }
    float v1 = -1e30f; i1 = (i0 == 0) ? 1 : 0;
#pragma unroll
    for (int j = 0; j < 8; ++j) if (j != i0 && probs[j] > v1) { v1 = probs[j]; i1 = j; }
    float wsum = v0 + v1 + 1e-9f;
    float w0 = v0 / wsum, w1 = v1 / wsum;

    out[IDX_OFF + (size_t)b * 2 + 0] = (float)i0;
    out[IDX_OFF + (size_t)b * 2 + 1] = (float)i1;
    out[SCO_OFF + (size_t)b * 2 + 0] = v0;
    out[SCO_OFF + (size_t)b * 2 + 1] = v1;
    selbuf[(size_t)b * 4 + 0] = (float)i0;
    selbuf[(size_t)b * 4 + 1] = (float)i1;
    selbuf[(size_t)b * 4 + 2] = w0;
    selbuf[(size_t)b * 4 + 3] = w1;

#pragma unroll
    for (int e2 = 0; e2 < 8; ++e2) {
      unsigned long long mm = __ballot(i0 == e2) | __ballot(i1 == e2);
      if (lane == 0) bcnt[((size_t)blockIdx.x * 2 + w) * 8 + e2] = __popcll(mm);
    }
#pragma unroll
    for (int j = 0; j < 8; ++j) {
      float p = probs[j];
#pragma unroll
      for (int mk = 1; mk <= 32; mk <<= 1) p += __shfl_xor(p, mk, 64);
      if (lane == 0) atomicAdd(&sprob[j], p);
    }
  }
  __syncthreads();
  if (tid < 8) atomicAdd(&aux[tid], sprob[tid]);
}

// scan of bcnt -> bbase,cnt, + aux_loss finalize (merged, one launch)
__global__ void k_scanaux(const int* __restrict__ bcnt, int* __restrict__ bbase,
                          int* __restrict__ cnt, const float* __restrict__ aux,
                          float* __restrict__ out) {
  __shared__ int psum[8][8];
  __shared__ int scnt[8];
  int tid = threadIdx.x;
  int e2 = tid & 7, seg = tid >> 3;
  int s = 0;
  for (int i = 0; i < 64; ++i) s += bcnt[(seg * 64 + i) * 8 + e2];
  psum[seg][e2] = s;
  __syncthreads();
  int base = 0;
  for (int t = 0; t < seg; ++t) base += psum[t][e2];
  int run = base;
  for (int i = 0; i < 64; ++i) {
    bbase[(seg * 64 + i) * 8 + e2] = run;
    run += bcnt[(seg * 64 + i) * 8 + e2];
  }
  if (seg == 7) { cnt[e2] = run; scnt[e2] = run; }
  __syncthreads();
  if (tid == 0) {
    float ss = 0.f;
#pragma unroll
    for (int e = 0; e < 8; ++e)
      ss += ((float)scnt[e] / 65536.f) * (aux[e] / 32768.f);
    out[AUX_OFF] = 8.f * ss;
  }
}

// fill perm sorted by row within each expert (deterministic, ballot ranks)
__global__ void k_fill(const float* __restrict__ selbuf, const int* __restrict__ bbase,
                       int* __restrict__ perm) {
  int gidx = blockIdx.x;          // 512 groups
  int lane = threadIdx.x;         // 64
  int b = gidx * 64 + lane;
  int i0 = (int)selbuf[(size_t)b * 4 + 0];
  int i1 = (int)selbuf[(size_t)b * 4 + 1];
  unsigned long long lt = (1ull << lane) - 1ull;
#pragma unroll
  for (int e2 = 0; e2 < 8; ++e2) {
    unsigned long long mm = __ballot(i0 == e2) | __ballot(i1 == e2);
    if (i0 == e2 || i1 == e2) {
      int s = bbase[gidx * 8 + e2] + (int)__popcll(mm & lt);
      if (s < CAP) perm[e2 * CAP + s] = b;
    }
  }
}

// ------- fused expert chain body (round-14/16 structure, LDS passed in) -------
template<int K1, int N1, int N2, bool GATHER, bool FCHAIN>
__device__ __forceinline__ void chain_body(
    int bid, char* ldsraw,
    const unsigned short* __restrict__ A, int As,
    const int* __restrict__ perm, const int* __restrict__ cnt,
    const unsigned short* __restrict__ W1, const float* __restrict__ b1v,
    const float* __restrict__ g1v, const float* __restrict__ h1v,
    const unsigned short* __restrict__ W2, const float* __restrict__ b2v,
    const float* __restrict__ g2v, const float* __restrict__ h2v,
    unsigned short* __restrict__ Out, int Os, int Ocol,
    const float* __restrict__ fw3, const float* __restrict__ fb3,
    float* __restrict__ allout) {
  constexpr int WC1 = N1 / 8, NF1 = WC1 / 16;
  constexpr int WC2 = N2 / 8, NF2 = WC2 / 16;
  constexpr int NK1 = K1 / 64;
  constexpr int NS1 = NK1 * 2, NS2 = (N1 / 64) * 2;
  constexpr int PAN = (K1 > N1) ? K1 : N1;
  constexpr int NCH = N2 / 128;
  static_assert(NF1 >= 1 && NF2 >= 1 && K1 % 64 == 0 && N1 % 128 == 0, "shape");

  unsigned short* smP = (unsigned short*)ldsraw;
  float (*red)[8][2] = (float(*)[8][2])(ldsraw + (size_t)64 * PAN * 2);
  float (*rowstat)[2] = (float(*)[2])(ldsraw + (size_t)64 * PAN * 2 + 4096);

  int e = bid & 7;              // expert-per-XCD L2 pinning
  int count = cnt[e]; if (count > CAP) count = CAP;
  int rb = (bid >> 3) * 64;
  if (rb >= count) return;

  int tid = threadIdx.x;
  int lane = tid & 63, wn = tid >> 6;
  int l15 = lane & 15, g = lane >> 4;

  // ---- stage A1 panel (64 x K1), single barrier ----
  {
    int srow = tid >> 3, schunk = tid & 7;
    int slot = rb + srow;
    size_t arow;
    if (GATHER) {
      int s = slot < count ? slot : count - 1;
      arow = (size_t)perm[e * CAP + s];
    } else {
      arow = (size_t)e * CAP + slot;
    }
    const unsigned short* aptr = A + arow * As + schunk * 8;
    int lws = srow * K1 + ((schunk ^ (srow & 7)) << 3);
    uint4 stg[NK1];
#pragma unroll
    for (int kt = 0; kt < NK1; ++kt) stg[kt] = *(const uint4*)(aptr + kt * 64);
#pragma unroll
    for (int kt = 0; kt < NK1; ++kt) *(uint4*)(&smP[lws + kt * 64]) = stg[kt];
  }

  // ---- GEMM1: acc1 = A1 @ W1 (ping-pong B queues) ----
  const unsigned short* W1e = W1 + (size_t)e * N1 * K1;
  const unsigned short* bp1[NF1];
#pragma unroll
  for (int nf = 0; nf < NF1; ++nf)
    bp1[nf] = W1e + (size_t)(wn * WC1 + nf * 16 + l15) * K1 + g * 8;

  f32x4 acc1[4][NF1] = {};
  bf16x8 qA[NF1], qB[NF1];
#pragma unroll
  for (int nf = 0; nf < NF1; ++nf) qA[nf] = *(const bf16x8*)(bp1[nf]);
  if (NS1 > 1) {
#pragma unroll
    for (int nf = 0; nf < NF1; ++nf) qB[nf] = *(const bf16x8*)(bp1[nf] + 32);
  }

  __syncthreads();

#pragma unroll
  for (int ks = 0; ks < NS1; ++ks) {
    const int kt = ks >> 1, kk = ks & 1;
    bf16x8 a4[4];
#pragma unroll
    for (int mf = 0; mf < 4; ++mf) {
      int row = mf * 16 + l15;
      int chunk = (kk * 4 + g) ^ (row & 7);
      a4[mf] = *(const bf16x8*)(&smP[row * K1 + kt * 64 + chunk * 8]);
    }
    if ((ks & 1) == 0) {
#pragma unroll
      for (int mf = 0; mf < 4; ++mf)
#pragma unroll
        for (int nf = 0; nf < NF1; ++nf)
          acc1[mf][nf] = __builtin_amdgcn_mfma_f32_16x16x32_bf16(a4[mf], qA[nf], acc1[mf][nf], 0, 0, 0);
      if (ks + 2 < NS1) {
#pragma unroll
        for (int nf = 0; nf < NF1; ++nf) qA[nf] = *(const bf16x8*)(bp1[nf] + (ks + 2) * 32);
      }
    } else {
#pragma unroll
      for (int mf = 0; mf < 4; ++mf)
#pragma unroll
        for (int nf = 0; nf < NF1; ++nf)
          acc1[mf][nf] = __builtin_amdgcn_mfma_f32_16x16x32_bf16(a4[mf], qB[nf], acc1[mf][nf], 0, 0, 0);
      if (ks + 2 < NS1) {
#pragma unroll
        for (int nf = 0; nf < NF1; ++nf) qB[nf] = *(const bf16x8*)(bp1[nf] + (ks + 2) * 32);
      }
    }
  }

  // ---- bias + ELU + LN over N1 ----
  {
    float bia[NF1], gam[NF1], bet[NF1];
#pragma unroll
    for (int nf = 0; nf < NF1; ++nf) {
      int n = wn * WC1 + nf * 16 + l15;
      bia[nf] = b1v[e * N1 + n]; gam[nf] = g1v[e * N1 + n]; bet[nf] = h1v[e * N1 + n];
    }
#pragma unroll
    for (int mf = 0; mf < 4; ++mf)
#pragma unroll
      for (int nf = 0; nf < NF1; ++nf)
#pragma unroll
        for (int r = 0; r < 4; ++r)
          acc1[mf][nf][r] = fast_elu(acc1[mf][nf][r] + bia[nf]);
#pragma unroll
    for (int mf = 0; mf < 4; ++mf)
#pragma unroll
      for (int r = 0; r < 4; ++r) {
        float s1 = 0.f, s2 = 0.f;
#pragma unroll
        for (int nf = 0; nf < NF1; ++nf) {
          float x = acc1[mf][nf][r];
          s1 += x; s2 += x * x;
        }
#pragma unroll
        for (int mk = 1; mk <= 8; mk <<= 1) {
          s1 += __shfl_xor(s1, mk, 64);
          s2 += __shfl_xor(s2, mk, 64);
        }
        if (l15 == 0) {
          int row = mf * 16 + g * 4 + r;
          red[row][wn][0] = s1;
          red[row][wn][1] = s2;
        }
      }
    __syncthreads();
    if (tid < 64) {
      float s1 = 0.f, s2 = 0.f;
#pragma unroll
      for (int j = 0; j < 8; ++j) { s1 += red[tid][j][0]; s2 += red[tid][j][1]; }
      float mean = s1 / (float)N1;
      float var = s2 / (float)N1 - mean * mean;
      rowstat[tid][0] = mean;
      rowstat[tid][1] = rsqrtf(var + 1e-5f);
    }
    __syncthreads();
#pragma unroll
    for (int mf = 0; mf < 4; ++mf)
#pragma unroll
      for (int r = 0; r < 4; ++r) {
        int row = mf * 16 + g * 4 + r;
        float mean = rowstat[row][0], rstd = rowstat[row][1];
#pragma unroll
        for (int nf = 0; nf < NF1; ++nf) {
          int col = wn * WC1 + nf * 16 + l15;
          float y = (acc1[mf][nf][r] - mean) * rstd * gam[nf] + bet[nf];
          int pos = (col & ~63) + ((((col >> 3) & 7) ^ (row & 7)) << 3) + (col & 7);
          smP[row * N1 + pos] = f2b(y);
        }
      }
  }

  // ---- GEMM2: acc2 = h1 @ W2 (ping-pong B queues) ----
  const unsigned short* W2e = W2 + (size_t)e * N2 * N1;
  const unsigned short* bp2[NF2];
#pragma unroll
  for (int nf = 0; nf < NF2; ++nf)
    bp2[nf] = W2e + (size_t)(wn * WC2 + nf * 16 + l15) * N1 + g * 8;

  f32x4 acc2[4][NF2] = {};
  bf16x8 pA[NF2], pB[NF2];
#pragma unroll
  for (int nf = 0; nf < NF2; ++nf) pA[nf] = *(const bf16x8*)(bp2[nf]);
  if (NS2 > 1) {
#pragma unroll
    for (int nf = 0; nf < NF2; ++nf) pB[nf] = *(const bf16x8*)(bp2[nf] + 32);
  }

  __syncthreads();   // h1 panel complete

#pragma unroll
  for (int ks = 0; ks < NS2; ++ks) {
    const int kt = ks >> 1, kk = ks & 1;
    bf16x8 a4[4];
#pragma unroll
    for (int mf = 0; mf < 4; ++mf) {
      int row = mf * 16 + l15;
      int chunk = (kk * 4 + g) ^ (row & 7);
      a4[mf] = *(const bf16x8*)(&smP[row * N1 + kt * 64 + chunk * 8]);
    }
    if ((ks & 1) == 0) {
#pragma unroll
      for (int mf = 0; mf < 4; ++mf)
#pragma unroll
        for (int nf = 0; nf < NF2; ++nf)
          acc2[mf][nf] = __builtin_amdgcn_mfma_f32_16x16x32_bf16(a4[mf], pA[nf], acc2[mf][nf], 0, 0, 0);
      if (ks + 2 < NS2) {
#pragma unroll
        for (int nf = 0; nf < NF2; ++nf) pA[nf] = *(const bf16x8*)(bp2[nf] + (ks + 2) * 32);
      }
    } else {
#pragma unroll
      for (int mf = 0; mf < 4; ++mf)
#pragma unroll
        for (int nf = 0; nf < NF2; ++nf)
          acc2[mf][nf] = __builtin_amdgcn_mfma_f32_16x16x32_bf16(a4[mf], pB[nf], acc2[mf][nf], 0, 0, 0);
      if (ks + 2 < NS2) {
#pragma unroll
        for (int nf = 0; nf < NF2; ++nf) pB[nf] = *(const bf16x8*)(bp2[nf] + (ks + 2) * 32);
      }
    }
  }

  // ---- bias + ELU + LN over N2 ----
  {
    float bia[NF2], gam[NF2], bet[NF2];
#pragma unroll
    for (int nf = 0; nf < NF2; ++nf) {
      int n = wn * WC2 + nf * 16 + l15;
      bia[nf] = b2v[e * N2 + n]; gam[nf] = g2v[e * N2 + n]; bet[nf] = h2v[e * N2 + n];
    }
#pragma unroll
    for (int mf = 0; mf < 4; ++mf)
#pragma unroll
      for (int nf = 0; nf < NF2; ++nf)
#pragma unroll
        for (int r = 0; r < 4; ++r)
          acc2[mf][nf][r] = fast_elu(acc2[mf][nf][r] + bia[nf]);
#pragma unroll
    for (int mf = 0; mf < 4; ++mf)
#pragma unroll
      for (int r = 0; r < 4; ++r) {
        float s1 = 0.f, s2 = 0.f;
#pragma unroll
        for (int nf = 0; nf < NF2; ++nf) {
          float x = acc2[mf][nf][r];
          s1 += x; s2 += x * x;
        }
#pragma unroll
        for (int mk = 1; mk <= 8; mk <<= 1) {
          s1 += __shfl_xor(s1, mk, 64);
          s2 += __shfl_xor(s2, mk, 64);
        }
        if (l15 == 0) {
          int row = mf * 16 + g * 4 + r;
          red[row][wn][0] = s1;
          red[row][wn][1] = s2;
        }
      }
    __syncthreads();
    if (tid < 64) {
      float s1 = 0.f, s2 = 0.f;
#pragma unroll
      for (int j = 0; j < 8; ++j) { s1 += red[tid][j][0]; s2 += red[tid][j][1]; }
      float mean = s1 / (float)N2;
      float var = s2 / (float)N2 - mean * mean;
      rowstat[tid][0] = mean;
      rowstat[tid][1] = rsqrtf(var + 1e-5f);
    }
    __syncthreads();
#pragma unroll
    for (int mf = 0; mf < 4; ++mf)
#pragma unroll
      for (int r = 0; r < 4; ++r) {
        int row = mf * 16 + g * 4 + r;
        float mean = rowstat[row][0], rstd = rowstat[row][1];
#pragma unroll
        for (int nf = 0; nf < NF2; ++nf)
          acc2[mf][nf][r] = (acc2[mf][nf][r] - mean) * rstd * gam[nf] + bet[nf];
      }
  }

  if constexpr (!FCHAIN) {
    // ---- vectorized store via LDS staging, 128-col chunks ----
    unsigned short* sm16 = &smP[0];
    int wq = (wn * WC2) >> 7;
    for (int q = 0; q < NCH; ++q) {
      __syncthreads();
      if (NCH == 1 || wq == q) {
#pragma unroll
        for (int mf = 0; mf < 4; ++mf)
#pragma unroll
          for (int r = 0; r < 4; ++r) {
            int row = mf * 16 + g * 4 + r;
            int s = row & 7;
#pragma unroll
            for (int nf = 0; nf < NF2; ++nf) {
              int lc = (wn * WC2 + nf * 16 + l15) - q * 128;
              if (NCH == 1 || (lc >= 0 && lc < 128)) {
                int pos = (((lc >> 3) ^ s) << 3) | (lc & 7);
                sm16[row * 128 + pos] = f2b(acc2[mf][nf][r]);
              }
            }
          }
      }
      __syncthreads();
#pragma unroll
      for (int i = 0; i < 2; ++i) {
        int t = tid + i * 512;
        int row = t >> 4, cc = t & 15;
        int oc = cc ^ (row & 7);
        uint4 v = *(const uint4*)(&sm16[row * 128 + cc * 8]);
        *(uint4*)(&Out[((size_t)e * CAP + rb + row) * Os + Ocol + q * 128 + oc * 8]) = v;
      }
    }
  } else {
    // ---- f-chain: h2 to LDS (padded) + fw3 staged to LDS, 256->12 head ----
    __syncthreads();
    constexpr int H2S = 264;
    float* wsh = (float*)(&smP[64 * H2S]);
#pragma unroll
    for (int mf = 0; mf < 4; ++mf)
#pragma unroll
      for (int r = 0; r < 4; ++r) {
        int row = mf * 16 + g * 4 + r;
#pragma unroll
        for (int nf = 0; nf < NF2; ++nf) {
          int col = wn * WC2 + nf * 16 + l15;
          smP[row * H2S + col] = f2b(acc2[mf][nf][r]);
        }
      }
    for (int i = tid; i < 256 * 12; i += 512) wsh[i] = fw3[(size_t)e * 256 * 12 + i];
    __syncthreads();
#pragma unroll
    for (int it = 0; it < 2; ++it) {
      int idx = tid + it * 512;
      if (idx < 768) {
        int row = idx / 12, j = idx - row * 12;
        int slot2 = rb + row;
        if (slot2 < count) {
          float a = fb3[e * 12 + j];
          for (int c = 0; c < 256; ++c)
            a += b2f(smP[row * H2S + c]) * wsh[c * 12 + j];
          int arow = perm[e * CAP + slot2];
          allout[((size_t)arow * 8 + e) * 12 + j] = a;
        }
      }
    }
  }
}

// merged s+v chains: block-specialized, one launch (fills each other's idle slots)
__launch_bounds__(512, 4)
__global__ void k_sv(const unsigned short* __restrict__ st_bf,
                     const unsigned short* __restrict__ vl_bf,
                     const int* __restrict__ perm, const int* __restrict__ cnt,
                     const unsigned short* __restrict__ wS1, const float* __restrict__ sb1,
                     const float* __restrict__ sg1, const float* __restrict__ sh1,
                     const unsigned short* __restrict__ wS2, const float* __restrict__ sb2,
                     const float* __restrict__ sg2, const float* __restrict__ sh2,
                     const unsigned short* __restrict__ wV1, const float* __restrict__ vb1,
                     const float* __restrict__ vg1, const float* __restrict__ vh1,
                     const unsigned short* __restrict__ wV2, const float* __restrict__ vb2,
                     const float* __restrict__ vg2, const float* __restrict__ vh2,
                     unsigned short* __restrict__ bufF) {
  __shared__ char lds[70144];
  int bid = blockIdx.x;
  if (bid < NBLKC) {
    chain_body<512, 512, 256, true, false>(bid, lds, vl_bf, 512, perm, cnt,
        wV1, vb1, vg1, vh1, wV2, vb2, vg2, vh2,
        bufF, 384, 128, nullptr, nullptr, nullptr);
  } else {
    chain_body<128, 256, 128, true, false>(bid - NBLKC, lds, st_bf, 128, perm, cnt,
        wS1, sb1, sg1, sh1, wS2, sb2, sg2, sh2,
        bufF, 384, 0, nullptr, nullptr, nullptr);
  }
}

__launch_bounds__(512, 4)
__global__ void k_chainF(const unsigned short* __restrict__ bufF,
                         const int* __restrict__ perm, const int* __restrict__ cnt,
                         const unsigned short* __restrict__ wF1, const float* __restrict__ fb1,
                         const float* __restrict__ fg1, const float* __restrict__ fh1,
                         const unsigned short* __restrict__ wF2, const float* __restrict__ fb2,
                         const float* __restrict__ fg2, const float* __restrict__ fh2,
                         const float* __restrict__ fw3, const float* __restrict__ fb3,
                         float* __restrict__ allout) {
  __shared__ char lds[70144];
  chain_body<384, 512, 256, false, true>(blockIdx.x, lds, bufF, 384, perm, cnt,
      wF1, fb1, fg1, fh1, wF2, fb2, fg2, fh2,
      nullptr, 0, 0, fw3, fb3, allout);
}

// ------- mix: weighted sum of the two selected expert outputs -------
__global__ void k_mix(const float* __restrict__ selbuf, const float* __restrict__ allout,
                      float* __restrict__ out) {
  int b = blockIdx.x * 256 + threadIdx.x;
  int i0 = (int)selbuf[(size_t)b * 4 + 0];
  int i1 = (int)selbuf[(size_t)b * 4 + 1];
  float w0 = selbuf[(size_t)b * 4 + 2];
  float w1 = selbuf[(size_t)b * 4 + 3];
  const float* a0 = allout + ((size_t)b * 8 + i0) * 12;
  const float* a1 = allout + ((size_t)b * 8 + i1) * 12;
#pragma unroll
  for (int j = 0; j < 12; ++j)
    out[(size_t)b * 12 + j] = w0 * a0[j] + w1 * a1[j];
}

// ---------------- host ----------------

extern "C" void kernel_launch(void* const* d_in, const int* in_sizes, int n_in,
                              void* d_out, int out_size, void* d_ws, size_t ws_size,
                              hipStream_t stream) {
  const float* state = (const float*)d_in[0];
  const float* vlm   = (const float*)d_in[1];
  const float* sw1 = (const float*)d_in[2];  const float* sb1 = (const float*)d_in[3];
  const float* sg1 = (const float*)d_in[4];  const float* sh1 = (const float*)d_in[5];
  const float* sw2 = (const float*)d_in[6];  const float* sb2 = (const float*)d_in[7];
  const float* sg2 = (const float*)d_in[8];  const float* sh2 = (const float*)d_in[9];
  const float* vw1 = (const float*)d_in[10]; const float* vb1 = (const float*)d_in[11];
  const float* vg1 = (const float*)d_in[12]; const float* vh1 = (const float*)d_in[13];
  const float* vw2 = (const float*)d_in[14]; const float* vb2 = (const float*)d_in[15];
  const float* vg2 = (const float*)d_in[16]; const float* vh2 = (const float*)d_in[17];
  const float* fw1 = (const float*)d_in[18]; const float* fb1 = (const float*)d_in[19];
  const float* fg1 = (const float*)d_in[20]; const float* fh1 = (const float*)d_in[21];
  const float* fw2 = (const float*)d_in[22]; const float* fb2 = (const float*)d_in[23];
  const float* fg2 = (const float*)d_in[24]; const float* fh2 = (const float*)d_in[25];
  const float* fw3 = (const float*)d_in[26]; const float* fb3 = (const float*)d_in[27];
  const float* gw1 = (const float*)d_in[28]; const float* gb1 = (const float*)d_in[29];
  const float* gw2 = (const float*)d_in[30]; const float* gb2 = (const float*)d_in[31];
  const float* gw3 = (const float*)d_in[32]; const float* gb3 = (const float*)d_in[33];

  // ---- workspace (~232 MB) ----
  char* ws = (char*)d_ws;
  size_t off = 0;
  auto alloc = [&](size_t bytes) -> char* {
    char* p = ws + off;
    off = (off + bytes + 255) & ~(size_t)255;
    return p;
  };
  unsigned short* st_bf = (unsigned short*)alloc((size_t)BROWS * 128 * 2);
  unsigned short* vl_bf = (unsigned short*)alloc((size_t)BROWS * 512 * 2);
  unsigned short* bufF  = (unsigned short*)alloc((size_t)NEXP * CAP * 384 * 2);
  float* allout = (float*)alloc((size_t)BROWS * 8 * 12 * 4);
  float* gh1a   = (float*)alloc((size_t)BROWS * 256 * 4);
  float* gh1b   = (float*)alloc((size_t)BROWS * 256 * 4);
  float* gh1    = (float*)alloc((size_t)BROWS * 256 * 4);
  float* selbuf = (float*)alloc((size_t)BROWS * 4 * 4);
  int*   perm   = (int*)alloc((size_t)NEXP * CAP * 4);
  int*   bcnt   = (int*)alloc(512 * 8 * 4);
  int*   bbase  = (int*)alloc(512 * 8 * 4);
  char*  cntaux = alloc(256);  // cnt: 8 ints at +0, aux: 8 floats at +64
  int*   cnt = (int*)cntaux;
  float* aux = (float*)(cntaux + 64);
  unsigned short* wt_s1 = (unsigned short*)alloc((size_t)8 * 256 * 128 * 2);
  unsigned short* wt_s2 = (unsigned short*)alloc((size_t)8 * 128 * 256 * 2);
  unsigned short* wt_v1 = (unsigned short*)alloc((size_t)8 * 512 * 512 * 2);
  unsigned short* wt_v2 = (unsigned short*)alloc((size_t)8 * 256 * 512 * 2);
  unsigned short* wt_f1 = (unsigned short*)alloc((size_t)8 * 512 * 384 * 2);
  unsigned short* wt_f2 = (unsigned short*)alloc((size_t)8 * 256 * 512 * 2);
  (void)ws_size; (void)in_sizes; (void)n_in; (void)out_size;

  float* outf = (float*)d_out;

  // front: split-K gate1 (1024 blocks, 4/CU; r20-measured 197us) + transposes + converts
  const int NBCV = (BROWS * 128) / 256 + (BROWS * 512) / 256;
  k_front<<<1024 + 6144 + NBCV, 256, 0, stream>>>(
      state, vlm, st_bf, vl_bf, (int*)cntaux, gw1, gh1a, gh1b,
      sw1, wt_s1, sw2, wt_s2, vw1, wt_v1, vw2, wt_v2, fw1, wt_f1, fw2, wt_f2);

  // split-K combine (streaming, ~18us) then the proven merged gate tail
  k_comb<<<(BROWS * 256) / (256 * 8), 256, 0, stream>>>(gh1a, gh1b, gb1, gh1);
  k_gtail<<<256, 256, 0, stream>>>(gh1, gw2, gb2, gw3, gb3, outf, aux, bcnt, selbuf);
  k_scanaux<<<1, 64, 0, stream>>>(bcnt, bbase, cnt, aux, outf);
  k_fill<<<512, 64, 0, stream>>>(selbuf, bbase, perm);

  // s+v chains merged (block-specialized) then f-chain
  k_sv<<<2 * NBLKC, 512, 0, stream>>>(st_bf, vl_bf, perm, cnt,
      wt_s1, sb1, sg1, sh1, wt_s2, sb2, sg2, sh2,
      wt_v1, vb1, vg1, vh1, wt_v2, vb2, vg2, vh2, bufF);
  k_chainF<<<NBLKC, 512, 0, stream>>>(bufF, perm, cnt,
      wt_f1, fb1, fg1, fh1, wt_f2, fb2, fg2, fh2, fw3, fb3, allout);

  k_mix<<<BROWS / 256, 256, 0, stream>>>(selbuf, allout, outf);
}

// Round 28
// 533.091 us; speedup vs baseline: 1.1443x; 1.1443x over previous
//
#include <hip/hip_runtime.h>
#include <cstdint>
#include <cstddef>

#define BROWS 32768
#define NEXP 8
#define CAP 10240          // per-expert row capacity (E[count]=8192, std~78)
#define CAPBLK (CAP / 64)
#define NBLKC (CAPBLK * NEXP)

typedef short bf16x8 __attribute__((ext_vector_type(8)));
typedef float f32x4 __attribute__((ext_vector_type(4)));
typedef float f32x2 __attribute__((ext_vector_type(2)));

__device__ __forceinline__ unsigned short f2b(float f) {
  union { float f; unsigned u; } v; v.f = f;
  unsigned r = (v.u + 0x7fffu + ((v.u >> 16) & 1u)) >> 16;
  return (unsigned short)r;
}
__device__ __forceinline__ float b2f(unsigned short s) {
  union { unsigned u; float f; } v; v.u = ((unsigned)s) << 16; return v.f;
}
__device__ __forceinline__ float fast_elu(float x) {
  return x > 0.f ? x : __expf(x) - 1.f;
}

// ---------------- gate GEMM body 128x128 (round-16 packed fp32) ----------------
template<bool TWOSRC>
__device__ __forceinline__ void gate_gemm_body(
    char* ldsraw, int rb, int nb,
    const float* __restrict__ A0, int As0,
    const float* __restrict__ A1, int As1, int Ks,
    const float* __restrict__ W, const float* __restrict__ bias,
    int K, int N, float* __restrict__ Out) {
  float (*At)[132] = (float(*)[132])ldsraw;
  float (*Bs)[132] = (float(*)[132])(ldsraw + 32 * 132 * 4);

  int tid = threadIdx.x;
  int tx = tid & 15, tyg = tid >> 4;
  int arow = tid >> 1, aq = (tid & 1) * 16;
  int brow = tid >> 3, bc = (tid & 7) * 16;

  f32x2 acc[8][4] = {};

  float4 a0, a1, a2, a3, b0, b1, b2, b3;
  {
    const float* arp = (!TWOSRC || aq < Ks)
        ? (A0 + (size_t)(rb + arow) * As0 + aq)
        : (A1 + (size_t)(rb + arow) * As1 + (aq - Ks));
    a0 = *(const float4*)(arp);
    a1 = *(const float4*)(arp + 4);
    a2 = *(const float4*)(arp + 8);
    a3 = *(const float4*)(arp + 12);
    const float* brp = W + (size_t)brow * N + nb + bc;
    b0 = *(const float4*)(brp);
    b1 = *(const float4*)(brp + 4);
    b2 = *(const float4*)(brp + 8);
    b3 = *(const float4*)(brp + 12);
  }

  const int NT = K / 32;
  for (int kt = 0; kt < NT; ++kt) {
    __syncthreads();
    At[aq + 0][arow] = a0.x;  At[aq + 1][arow] = a0.y;
    At[aq + 2][arow] = a0.z;  At[aq + 3][arow] = a0.w;
    At[aq + 4][arow] = a1.x;  At[aq + 5][arow] = a1.y;
    At[aq + 6][arow] = a1.z;  At[aq + 7][arow] = a1.w;
    At[aq + 8][arow] = a2.x;  At[aq + 9][arow] = a2.y;
    At[aq + 10][arow] = a2.z; At[aq + 11][arow] = a2.w;
    At[aq + 12][arow] = a3.x; At[aq + 13][arow] = a3.y;
    At[aq + 14][arow] = a3.z; At[aq + 15][arow] = a3.w;
    *(float4*)(&Bs[brow][bc])      = b0;
    *(float4*)(&Bs[brow][bc + 4])  = b1;
    *(float4*)(&Bs[brow][bc + 8])  = b2;
    *(float4*)(&Bs[brow][bc + 12]) = b3;
    __syncthreads();

    if (kt + 1 < NT) {
      int ka = (kt + 1) * 32 + aq;
      const float* arp = (!TWOSRC || ka < Ks)
          ? (A0 + (size_t)(rb + arow) * As0 + ka)
          : (A1 + (size_t)(rb + arow) * As1 + (ka - Ks));
      a0 = *(const float4*)(arp);
      a1 = *(const float4*)(arp + 4);
      a2 = *(const float4*)(arp + 8);
      a3 = *(const float4*)(arp + 12);
      const float* brp = W + (size_t)((kt + 1) * 32 + brow) * N + nb + bc;
      b0 = *(const float4*)(brp);
      b1 = *(const float4*)(brp + 4);
      b2 = *(const float4*)(brp + 8);
      b3 = *(const float4*)(brp + 12);
    }

#pragma unroll 4
    for (int kk = 0; kk < 32; ++kk) {
      float4 av0 = *(const float4*)(&At[kk][tyg * 8]);
      float4 av1 = *(const float4*)(&At[kk][tyg * 8 + 4]);
      float4 bq0 = *(const float4*)(&Bs[kk][tx * 8]);
      float4 bq1 = *(const float4*)(&Bs[kk][tx * 8 + 4]);
      f32x2 bp0 = {bq0.x, bq0.y}, bp1 = {bq0.z, bq0.w};
      f32x2 bp2 = {bq1.x, bq1.y}, bp3 = {bq1.z, bq1.w};
      float av[8] = {av0.x, av0.y, av0.z, av0.w, av1.x, av1.y, av1.z, av1.w};
#pragma unroll
      for (int i = 0; i < 8; ++i) {
        f32x2 as = {av[i], av[i]};
        acc[i][0] = __builtin_elementwise_fma(as, bp0, acc[i][0]);
        acc[i][1] = __builtin_elementwise_fma(as, bp1, acc[i][1]);
        acc[i][2] = __builtin_elementwise_fma(as, bp2, acc[i][2]);
        acc[i][3] = __builtin_elementwise_fma(as, bp3, acc[i][3]);
      }
    }
  }

  float4 bia0 = *(const float4*)(&bias[nb + tx * 8]);
  float4 bia1 = *(const float4*)(&bias[nb + tx * 8 + 4]);
  float bia[8] = {bia0.x, bia0.y, bia0.z, bia0.w, bia1.x, bia1.y, bia1.z, bia1.w};

#pragma unroll
  for (int i = 0; i < 8; ++i) {
    float o[8];
#pragma unroll
    for (int j = 0; j < 4; ++j) {
      o[2 * j]     = acc[i][j][0] + bia[2 * j];
      o[2 * j + 1] = acc[i][j][1] + bia[2 * j + 1];
    }
#pragma unroll
    for (int j = 0; j < 8; ++j) o[j] = (o[j] > 0.f) ? o[j] : expm1f(o[j]);
    size_t orow = (size_t)(rb + tyg * 8 + i) * N + nb + tx * 8;
    float4 w0; w0.x = o[0]; w0.y = o[1]; w0.z = o[2]; w0.w = o[3];
    float4 w1; w1.x = o[4]; w1.y = o[5]; w1.z = o[6]; w1.w = o[7];
    *(float4*)(&Out[orow]) = w0;
    *(float4*)(&Out[orow + 4]) = w1;
  }
}

// ---------------- k_front: gate1 GEMM + all weight transposes + input converts ----------------
__launch_bounds__(256, 4)
__global__ void k_front(const float* __restrict__ state, const float* __restrict__ vlm,
                        unsigned short* __restrict__ st_bf, unsigned short* __restrict__ vl_bf,
                        int* __restrict__ cntaux,
                        const float* __restrict__ gw1, const float* __restrict__ gb1,
                        float* __restrict__ gh1,
                        const float* __restrict__ s1w, unsigned short* __restrict__ s1d,
                        const float* __restrict__ s2w, unsigned short* __restrict__ s2d,
                        const float* __restrict__ v1w, unsigned short* __restrict__ v1d,
                        const float* __restrict__ v2w, unsigned short* __restrict__ v2d,
                        const float* __restrict__ f1w, unsigned short* __restrict__ f1d,
                        const float* __restrict__ f2w, unsigned short* __restrict__ f2d) {
  __shared__ char lds[2 * 32 * 132 * 4];   // 33792 B (gate path); wtrans uses prefix
  int bid = blockIdx.x, tid = threadIdx.x;

  if (bid < 512) {
    int rb = (bid & 255) * 128, nb = (bid >> 8) * 128;
    gate_gemm_body<true>(lds, rb, nb, state, 96, vlm, 512, 96,
                         gw1, gb1, 608, 256, gh1);
  } else if (bid < 512 + 6144) {
    float (*tile)[33] = (float(*)[33])lds;
    int b2 = bid - 512;
    int e = b2 / 768, r = b2 % 768;
    const float* src; unsigned short* dst; int K, N, Kpad, nbx;
    if (r < 32)       { src = s1w; dst = s1d; K = 96;  N = 256; Kpad = 128; nbx = 4;  }
    else if (r < 64)  { src = s2w; dst = s2d; K = 256; N = 128; Kpad = 256; nbx = 8;  r -= 32;  }
    else if (r < 320) { src = v1w; dst = v1d; K = 512; N = 512; Kpad = 512; nbx = 16; r -= 64;  }
    else if (r < 448) { src = v2w; dst = v2d; K = 512; N = 256; Kpad = 512; nbx = 16; r -= 320; }
    else if (r < 640) { src = f1w; dst = f1d; K = 384; N = 512; Kpad = 384; nbx = 12; r -= 448; }
    else              { src = f2w; dst = f2d; K = 512; N = 256; Kpad = 512; nbx = 16; r -= 640; }
    int k0 = (r % nbx) * 32, n0 = (r / nbx) * 32;
    int tx = tid & 31, ty = tid >> 5;   // 32 x 8
    for (int i = 0; i < 32; i += 8) {
      int k = k0 + ty + i;
      tile[ty + i][tx] = (k < K) ? src[((size_t)e * K + k) * N + n0 + tx] : 0.f;
    }
    __syncthreads();
    for (int i = 0; i < 32; i += 8) {
      int n = n0 + ty + i;
      dst[((size_t)e * N + n) * Kpad + k0 + tx] = f2b(tile[tx][ty + i]);
    }
  } else {
    int cid = bid - (512 + 6144);
    if (cid == 0 && tid < 64) cntaux[tid] = 0;
    const int NB1 = (BROWS * 128) / 256;
    if (cid < NB1) {
      int i = cid * 256 + tid;
      int r = i >> 7, c = i & 127;
      st_bf[i] = f2b(c < 96 ? state[(size_t)r * 96 + c] : 0.f);
    } else {
      int i = (cid - NB1) * 256 + tid;
      vl_bf[i] = f2b(vlm[i]);
    }
  }
}

// ------- merged gate tail: gate2 GEMM (128 rows/block) + logits/top2 in-block -------
#define ACTION_SZ (32768 * 12)
#define AUX_OFF   ACTION_SZ
#define IDX_OFF   (ACTION_SZ + 1)
#define SCO_OFF   (ACTION_SZ + 1 + 32768 * 2)

__launch_bounds__(256, 2)
__global__ void k_gtail(const float* __restrict__ gh1,
                        const float* __restrict__ gw2, const float* __restrict__ gb2,
                        const float* __restrict__ gw3, const float* __restrict__ gb3,
                        float* __restrict__ out, float* __restrict__ aux,
                        int* __restrict__ bcnt, float* __restrict__ selbuf) {
  __shared__ char lds[71680];
  float (*At)[132] = (float(*)[132])lds;
  float (*Bs)[132] = (float(*)[132])(lds + 32 * 132 * 4);
  float (*ghT)[132] = (float(*)[132])lds;        // phase 2: [col 0..127][row 0..127]
  float* gw3s = (float*)(lds + 67584);           // 128*8 floats (4KB)
  __shared__ float sprob[8];

  int tid = threadIdx.x;
  int rb = blockIdx.x * 128;
  int tx = tid & 15, tyg = tid >> 4;
  int arow = tid >> 1, aq = (tid & 1) * 16;
  int brow = tid >> 3, bc = (tid & 7) * 16;
  const int N = 128, K = 256;

  f32x2 acc[8][4] = {};
  float4 a0, a1, a2, a3, b0, b1, b2, b3;
  {
    const float* arp = gh1 + (size_t)(rb + arow) * 256 + aq;
    a0 = *(const float4*)(arp);
    a1 = *(const float4*)(arp + 4);
    a2 = *(const float4*)(arp + 8);
    a3 = *(const float4*)(arp + 12);
    const float* brp = gw2 + (size_t)brow * N + bc;
    b0 = *(const float4*)(brp);
    b1 = *(const float4*)(brp + 4);
    b2 = *(const float4*)(brp + 8);
    b3 = *(const float4*)(brp + 12);
  }
  const int NT = K / 32;
  for (int kt = 0; kt < NT; ++kt) {
    __syncthreads();
    At[aq + 0][arow] = a0.x;  At[aq + 1][arow] = a0.y;
    At[aq + 2][arow] = a0.z;  At[aq + 3][arow] = a0.w;
    At[aq + 4][arow] = a1.x;  At[aq + 5][arow] = a1.y;
    At[aq + 6][arow] = a1.z;  At[aq + 7][arow] = a1.w;
    At[aq + 8][arow] = a2.x;  At[aq + 9][arow] = a2.y;
    At[aq + 10][arow] = a2.z; At[aq + 11][arow] = a2.w;
    At[aq + 12][arow] = a3.x; At[aq + 13][arow] = a3.y;
    At[aq + 14][arow] = a3.z; At[aq + 15][arow] = a3.w;
    *(float4*)(&Bs[brow][bc])      = b0;
    *(float4*)(&Bs[brow][bc + 4])  = b1;
    *(float4*)(&Bs[brow][bc + 8])  = b2;
    *(float4*)(&Bs[brow][bc + 12]) = b3;
    __syncthreads();

    if (kt + 1 < NT) {
      int ka = (kt + 1) * 32 + aq;
      const float* arp = gh1 + (size_t)(rb + arow) * 256 + ka;
      a0 = *(const float4*)(arp);
      a1 = *(const float4*)(arp + 4);
      a2 = *(const float4*)(arp + 8);
      a3 = *(const float4*)(arp + 12);
      const float* brp = gw2 + (size_t)((kt + 1) * 32 + brow) * N + bc;
      b0 = *(const float4*)(brp);
      b1 = *(const float4*)(brp + 4);
      b2 = *(const float4*)(brp + 8);
      b3 = *(const float4*)(brp + 12);
    }

#pragma unroll 4
    for (int kk = 0; kk < 32; ++kk) {
      float4 av0 = *(const float4*)(&At[kk][tyg * 8]);
      float4 av1 = *(const float4*)(&At[kk][tyg * 8 + 4]);
      float4 bq0 = *(const float4*)(&Bs[kk][tx * 8]);
      float4 bq1 = *(const float4*)(&Bs[kk][tx * 8 + 4]);
      f32x2 bp0 = {bq0.x, bq0.y}, bp1 = {bq0.z, bq0.w};
      f32x2 bp2 = {bq1.x, bq1.y}, bp3 = {bq1.z, bq1.w};
      float av[8] = {av0.x, av0.y, av0.z, av0.w, av1.x, av1.y, av1.z, av1.w};
#pragma unroll
      for (int i = 0; i < 8; ++i) {
        f32x2 as = {av[i], av[i]};
        acc[i][0] = __builtin_elementwise_fma(as, bp0, acc[i][0]);
        acc[i][1] = __builtin_elementwise_fma(as, bp1, acc[i][1]);
        acc[i][2] = __builtin_elementwise_fma(as, bp2, acc[i][2]);
        acc[i][3] = __builtin_elementwise_fma(as, bp3, acc[i][3]);
      }
    }
  }

  float4 bia0 = *(const float4*)(&gb2[tx * 8]);
  float4 bia1 = *(const float4*)(&gb2[tx * 8 + 4]);
  float bia[8] = {bia0.x, bia0.y, bia0.z, bia0.w, bia1.x, bia1.y, bia1.z, bia1.w};

  __syncthreads();
  if (tid < 8) sprob[tid] = 0.f;
#pragma unroll
  for (int i = 0; i < 8; ++i) {
    int lr = tyg * 8 + i;
#pragma unroll
    for (int j = 0; j < 4; ++j) {
      float o0 = acc[i][j][0] + bia[2 * j];
      float o1 = acc[i][j][1] + bia[2 * j + 1];
      o0 = (o0 > 0.f) ? o0 : expm1f(o0);
      o1 = (o1 > 0.f) ? o1 : expm1f(o1);
      ghT[tx * 8 + 2 * j][lr] = o0;
      ghT[tx * 8 + 2 * j + 1][lr] = o1;
    }
  }
  for (int i = tid; i < 128 * 8; i += 256) gw3s[i] = gw3[i];
  __syncthreads();

  if (tid < 128) {
    int b = rb + tid;
    int lane = tid & 63, w = tid >> 6;
    float lg[8];
#pragma unroll
    for (int j = 0; j < 8; ++j) lg[j] = gb3[j];
    for (int k = 0; k < 128; ++k) {
      float h = ghT[k][tid];
#pragma unroll
      for (int j = 0; j < 8; ++j) lg[j] += h * gw3s[k * 8 + j];
    }
    float m = lg[0];
#pragma unroll
    for (int j = 1; j < 8; ++j) m = fmaxf(m, lg[j]);
    float probs[8], sum = 0.f;
#pragma unroll
    for (int j = 0; j < 8; ++j) { float p = expf(lg[j] - m); probs[j] = p; sum += p; }
    float inv = 1.f / sum;
#pragma unroll
    for (int j = 0; j < 8; ++j) probs[j] *= inv;
    int i0 = 0, i1;
    float v0 = -1e30f;
#pragma unroll
    for (int j = 0; j < 8; ++j) if (probs[j] > v0) { v0 = probs[j]; i0 = j; }
    float v1 = -1e30f; i1 = (i0 == 0) ? 1 : 0;
#pragma unroll
    for (int j = 0; j < 8; ++j) if (j != i0 && probs[j] > v1) { v1 = probs[j]; i1 = j; }
    float wsum = v0 + v1 + 1e-9f;
    float w0 = v0 / wsum, w1 = v1 / wsum;

    out[IDX_OFF + (size_t)b * 2 + 0] = (float)i0;
    out[IDX_OFF + (size_t)b * 2 + 1] = (float)i1;
    out[SCO_OFF + (size_t)b * 2 + 0] = v0;
    out[SCO_OFF + (size_t)b * 2 + 1] = v1;
    selbuf[(size_t)b * 4 + 0] = (float)i0;
    selbuf[(size_t)b * 4 + 1] = (float)i1;
    selbuf[(size_t)b * 4 + 2] = w0;
    selbuf[(size_t)b * 4 + 3] = w1;

#pragma unroll
    for (int e2 = 0; e2 < 8; ++e2) {
      unsigned long long mm = __ballot(i0 == e2) | __ballot(i1 == e2);
      if (lane == 0) bcnt[((size_t)blockIdx.x * 2 + w) * 8 + e2] = __popcll(mm);
    }
#pragma unroll
    for (int j = 0; j < 8; ++j) {
      float p = probs[j];
#pragma unroll
      for (int mk = 1; mk <= 32; mk <<= 1) p += __shfl_xor(p, mk, 64);
      if (lane == 0) atomicAdd(&sprob[j], p);
    }
  }
  __syncthreads();
  if (tid < 8) atomicAdd(&aux[tid], sprob[tid]);
}

// scan of bcnt -> bbase,cnt, + aux_loss finalize (merged, one launch)
__global__ void k_scanaux(const int* __restrict__ bcnt, int* __restrict__ bbase,
                          int* __restrict__ cnt, const float* __restrict__ aux,
                          float* __restrict__ out) {
  __shared__ int psum[8][8];
  __shared__ int scnt[8];
  int tid = threadIdx.x;
  int e2 = tid & 7, seg = tid >> 3;
  int s = 0;
  for (int i = 0; i < 64; ++i) s += bcnt[(seg * 64 + i) * 8 + e2];
  psum[seg][e2] = s;
  __syncthreads();
  int base = 0;
  for (int t = 0; t < seg; ++t) base += psum[t][e2];
  int run = base;
  for (int i = 0; i < 64; ++i) {
    bbase[(seg * 64 + i) * 8 + e2] = run;
    run += bcnt[(seg * 64 + i) * 8 + e2];
  }
  if (seg == 7) { cnt[e2] = run; scnt[e2] = run; }
  __syncthreads();
  if (tid == 0) {
    float ss = 0.f;
#pragma unroll
    for (int e = 0; e < 8; ++e)
      ss += ((float)scnt[e] / 65536.f) * (aux[e] / 32768.f);
    out[AUX_OFF] = 8.f * ss;
  }
}

// fill perm sorted by row within each expert (deterministic, ballot ranks)
__global__ void k_fill(const float* __restrict__ selbuf, const int* __restrict__ bbase,
                       int* __restrict__ perm) {
  int gidx = blockIdx.x;          // 512 groups
  int lane = threadIdx.x;         // 64
  int b = gidx * 64 + lane;
  int i0 = (int)selbuf[(size_t)b * 4 + 0];
  int i1 = (int)selbuf[(size_t)b * 4 + 1];
  unsigned long long lt = (1ull << lane) - 1ull;
#pragma unroll
  for (int e2 = 0; e2 < 8; ++e2) {
    unsigned long long mm = __ballot(i0 == e2) | __ballot(i1 == e2);
    if (i0 == e2 || i1 == e2) {
      int s = bbase[gidx * 8 + e2] + (int)__popcll(mm & lt);
      if (s < CAP) perm[e2 * CAP + s] = b;
    }
  }
}

// ------- fused expert chain body (round-14/16 structure, LDS passed in) -------
template<int K1, int N1, int N2, bool GATHER, bool FCHAIN>
__device__ __forceinline__ void chain_body(
    int bid, char* ldsraw,
    const unsigned short* __restrict__ A, int As,
    const int* __restrict__ perm, const int* __restrict__ cnt,
    const unsigned short* __restrict__ W1, const float* __restrict__ b1v,
    const float* __restrict__ g1v, const float* __restrict__ h1v,
    const unsigned short* __restrict__ W2, const float* __restrict__ b2v,
    const float* __restrict__ g2v, const float* __restrict__ h2v,
    unsigned short* __restrict__ Out, int Os, int Ocol,
    const float* __restrict__ fw3, const float* __restrict__ fb3,
    float* __restrict__ allout) {
  constexpr int WC1 = N1 / 8, NF1 = WC1 / 16;
  constexpr int WC2 = N2 / 8, NF2 = WC2 / 16;
  constexpr int NK1 = K1 / 64;
  constexpr int NS1 = NK1 * 2, NS2 = (N1 / 64) * 2;
  constexpr int PAN = (K1 > N1) ? K1 : N1;
  constexpr int NCH = N2 / 128;
  static_assert(NF1 >= 1 && NF2 >= 1 && K1 % 64 == 0 && N1 % 128 == 0, "shape");

  unsigned short* smP = (unsigned short*)ldsraw;
  float (*red)[8][2] = (float(*)[8][2])(ldsraw + (size_t)64 * PAN * 2);
  float (*rowstat)[2] = (float(*)[2])(ldsraw + (size_t)64 * PAN * 2 + 4096);

  int e = bid & 7;              // expert-per-XCD L2 pinning
  int count = cnt[e]; if (count > CAP) count = CAP;
  int rb = (bid >> 3) * 64;
  if (rb >= count) return;

  int tid = threadIdx.x;
  int lane = tid & 63, wn = tid >> 6;
  int l15 = lane & 15, g = lane >> 4;

  // ---- stage A1 panel (64 x K1), single barrier ----
  {
    int srow = tid >> 3, schunk = tid & 7;
    int slot = rb + srow;
    size_t arow;
    if (GATHER) {
      int s = slot < count ? slot : count - 1;
      arow = (size_t)perm[e * CAP + s];
    } else {
      arow = (size_t)e * CAP + slot;
    }
    const unsigned short* aptr = A + arow * As + schunk * 8;
    int lws = srow * K1 + ((schunk ^ (srow & 7)) << 3);
    uint4 stg[NK1];
#pragma unroll
    for (int kt = 0; kt < NK1; ++kt) stg[kt] = *(const uint4*)(aptr + kt * 64);
#pragma unroll
    for (int kt = 0; kt < NK1; ++kt) *(uint4*)(&smP[lws + kt * 64]) = stg[kt];
  }

  // ---- GEMM1: acc1 = A1 @ W1 (ping-pong B queues) ----
  const unsigned short* W1e = W1 + (size_t)e * N1 * K1;
  const unsigned short* bp1[NF1];
#pragma unroll
  for (int nf = 0; nf < NF1; ++nf)
    bp1[nf] = W1e + (size_t)(wn * WC1 + nf * 16 + l15) * K1 + g * 8;

  f32x4 acc1[4][NF1] = {};
  bf16x8 qA[NF1], qB[NF1];
#pragma unroll
  for (int nf = 0; nf < NF1; ++nf) qA[nf] = *(const bf16x8*)(bp1[nf]);
  if (NS1 > 1) {
#pragma unroll
    for (int nf = 0; nf < NF1; ++nf) qB[nf] = *(const bf16x8*)(bp1[nf] + 32);
  }

  __syncthreads();

#pragma unroll
  for (int ks = 0; ks < NS1; ++ks) {
    const int kt = ks >> 1, kk = ks & 1;
    bf16x8 a4[4];
#pragma unroll
    for (int mf = 0; mf < 4; ++mf) {
      int row = mf * 16 + l15;
      int chunk = (kk * 4 + g) ^ (row & 7);
      a4[mf] = *(const bf16x8*)(&smP[row * K1 + kt * 64 + chunk * 8]);
    }
    if ((ks & 1) == 0) {
#pragma unroll
      for (int mf = 0; mf < 4; ++mf)
#pragma unroll
        for (int nf = 0; nf < NF1; ++nf)
          acc1[mf][nf] = __builtin_amdgcn_mfma_f32_16x16x32_bf16(a4[mf], qA[nf], acc1[mf][nf], 0, 0, 0);
      if (ks + 2 < NS1) {
#pragma unroll
        for (int nf = 0; nf < NF1; ++nf) qA[nf] = *(const bf16x8*)(bp1[nf] + (ks + 2) * 32);
      }
    } else {
#pragma unroll
      for (int mf = 0; mf < 4; ++mf)
#pragma unroll
        for (int nf = 0; nf < NF1; ++nf)
          acc1[mf][nf] = __builtin_amdgcn_mfma_f32_16x16x32_bf16(a4[mf], qB[nf], acc1[mf][nf], 0, 0, 0);
      if (ks + 2 < NS1) {
#pragma unroll
        for (int nf = 0; nf < NF1; ++nf) qB[nf] = *(const bf16x8*)(bp1[nf] + (ks + 2) * 32);
      }
    }
  }

  // ---- bias + ELU + LN over N1 ----
  {
    float bia[NF1], gam[NF1], bet[NF1];
#pragma unroll
    for (int nf = 0; nf < NF1; ++nf) {
      int n = wn * WC1 + nf * 16 + l15;
      bia[nf] = b1v[e * N1 + n]; gam[nf] = g1v[e * N1 + n]; bet[nf] = h1v[e * N1 + n];
    }
#pragma unroll
    for (int mf = 0; mf < 4; ++mf)
#pragma unroll
      for (int nf = 0; nf < NF1; ++nf)
#pragma unroll
        for (int r = 0; r < 4; ++r)
          acc1[mf][nf][r] = fast_elu(acc1[mf][nf][r] + bia[nf]);
#pragma unroll
    for (int mf = 0; mf < 4; ++mf)
#pragma unroll
      for (int r = 0; r < 4; ++r) {
        float s1 = 0.f, s2 = 0.f;
#pragma unroll
        for (int nf = 0; nf < NF1; ++nf) {
          float x = acc1[mf][nf][r];
          s1 += x; s2 += x * x;
        }
#pragma unroll
        for (int mk = 1; mk <= 8; mk <<= 1) {
          s1 += __shfl_xor(s1, mk, 64);
          s2 += __shfl_xor(s2, mk, 64);
        }
        if (l15 == 0) {
          int row = mf * 16 + g * 4 + r;
          red[row][wn][0] = s1;
          red[row][wn][1] = s2;
        }
      }
    __syncthreads();
    if (tid < 64) {
      float s1 = 0.f, s2 = 0.f;
#pragma unroll
      for (int j = 0; j < 8; ++j) { s1 += red[tid][j][0]; s2 += red[tid][j][1]; }
      float mean = s1 / (float)N1;
      float var = s2 / (float)N1 - mean * mean;
      rowstat[tid][0] = mean;
      rowstat[tid][1] = rsqrtf(var + 1e-5f);
    }
    __syncthreads();
#pragma unroll
    for (int mf = 0; mf < 4; ++mf)
#pragma unroll
      for (int r = 0; r < 4; ++r) {
        int row = mf * 16 + g * 4 + r;
        float mean = rowstat[row][0], rstd = rowstat[row][1];
#pragma unroll
        for (int nf = 0; nf < NF1; ++nf) {
          int col = wn * WC1 + nf * 16 + l15;
          float y = (acc1[mf][nf][r] - mean) * rstd * gam[nf] + bet[nf];
          int pos = (col & ~63) + ((((col >> 3) & 7) ^ (row & 7)) << 3) + (col & 7);
          smP[row * N1 + pos] = f2b(y);
        }
      }
  }

  // ---- GEMM2: acc2 = h1 @ W2 (ping-pong B queues) ----
  const unsigned short* W2e = W2 + (size_t)e * N2 * N1;
  const unsigned short* bp2[NF2];
#pragma unroll
  for (int nf = 0; nf < NF2; ++nf)
    bp2[nf] = W2e + (size_t)(wn * WC2 + nf * 16 + l15) * N1 + g * 8;

  f32x4 acc2[4][NF2] = {};
  bf16x8 pA[NF2], pB[NF2];
#pragma unroll
  for (int nf = 0; nf < NF2; ++nf) pA[nf] = *(const bf16x8*)(bp2[nf]);
  if (NS2 > 1) {
#pragma unroll
    for (int nf = 0; nf < NF2; ++nf) pB[nf] = *(const bf16x8*)(bp2[nf] + 32);
  }

  __syncthreads();   // h1 panel complete

#pragma unroll
  for (int ks = 0; ks < NS2; ++ks) {
    const int kt = ks >> 1, kk = ks & 1;
    bf16x8 a4[4];
#pragma unroll
    for (int mf = 0; mf < 4; ++mf) {
      int row = mf * 16 + l15;
      int chunk = (kk * 4 + g) ^ (row & 7);
      a4[mf] = *(const bf16x8*)(&smP[row * N1 + kt * 64 + chunk * 8]);
    }
    if ((ks & 1) == 0) {
#pragma unroll
      for (int mf = 0; mf < 4; ++mf)
#pragma unroll
        for (int nf = 0; nf < NF2; ++nf)
          acc2[mf][nf] = __builtin_amdgcn_mfma_f32_16x16x32_bf16(a4[mf], pA[nf], acc2[mf][nf], 0, 0, 0);
      if (ks + 2 < NS2) {
#pragma unroll
        for (int nf = 0; nf < NF2; ++nf) pA[nf] = *(const bf16x8*)(bp2[nf] + (ks + 2) * 32);
      }
    } else {
#pragma unroll
      for (int mf = 0; mf < 4; ++mf)
#pragma unroll
        for (int nf = 0; nf < NF2; ++nf)
          acc2[mf][nf] = __builtin_amdgcn_mfma_f32_16x16x32_bf16(a4[mf], pB[nf], acc2[mf][nf], 0, 0, 0);
      if (ks + 2 < NS2) {
#pragma unroll
        for (int nf = 0; nf < NF2; ++nf) pB[nf] = *(const bf16x8*)(bp2[nf] + (ks + 2) * 32);
      }
    }
  }

  // ---- bias + ELU + LN over N2 ----
  {
    float bia[NF2], gam[NF2], bet[NF2];
#pragma unroll
    for (int nf = 0; nf < NF2; ++nf) {
      int n = wn * WC2 + nf * 16 + l15;
      bia[nf] = b2v[e * N2 + n]; gam[nf] = g2v[e * N2 + n]; bet[nf] = h2v[e * N2 + n];
    }
#pragma unroll
    for (int mf = 0; mf < 4; ++mf)
#pragma unroll
      for (int nf = 0; nf < NF2; ++nf)
#pragma unroll
        for (int r = 0; r < 4; ++r)
          acc2[mf][nf][r] = fast_elu(acc2[mf][nf][r] + bia[nf]);
#pragma unroll
    for (int mf = 0; mf < 4; ++mf)
#pragma unroll
      for (int r = 0; r < 4; ++r) {
        float s1 = 0.f, s2 = 0.f;
#pragma unroll
        for (int nf = 0; nf < NF2; ++nf) {
          float x = acc2[mf][nf][r];
          s1 += x; s2 += x * x;
        }
#pragma unroll
        for (int mk = 1; mk <= 8; mk <<= 1) {
          s1 += __shfl_xor(s1, mk, 64);
          s2 += __shfl_xor(s2, mk, 64);
        }
        if (l15 == 0) {
          int row = mf * 16 + g * 4 + r;
          red[row][wn][0] = s1;
          red[row][wn][1] = s2;
        }
      }
    __syncthreads();
    if (tid < 64) {
      float s1 = 0.f, s2 = 0.f;
#pragma unroll
      for (int j = 0; j < 8; ++j) { s1 += red[tid][j][0]; s2 += red[tid][j][1]; }
      float mean = s1 / (float)N2;
      float var = s2 / (float)N2 - mean * mean;
      rowstat[tid][0] = mean;
      rowstat[tid][1] = rsqrtf(var + 1e-5f);
    }
    __syncthreads();
#pragma unroll
    for (int mf = 0; mf < 4; ++mf)
#pragma unroll
      for (int r = 0; r < 4; ++r) {
        int row = mf * 16 + g * 4 + r;
        float mean = rowstat[row][0], rstd = rowstat[row][1];
#pragma unroll
        for (int nf = 0; nf < NF2; ++nf)
          acc2[mf][nf][r] = (acc2[mf][nf][r] - mean) * rstd * gam[nf] + bet[nf];
      }
  }

  if constexpr (!FCHAIN) {
    // ---- vectorized store via LDS staging, 128-col chunks ----
    unsigned short* sm16 = &smP[0];
    int wq = (wn * WC2) >> 7;
    for (int q = 0; q < NCH; ++q) {
      __syncthreads();
      if (NCH == 1 || wq == q) {
#pragma unroll
        for (int mf = 0; mf < 4; ++mf)
#pragma unroll
          for (int r = 0; r < 4; ++r) {
            int row = mf * 16 + g * 4 + r;
            int s = row & 7;
#pragma unroll
            for (int nf = 0; nf < NF2; ++nf) {
              int lc = (wn * WC2 + nf * 16 + l15) - q * 128;
              if (NCH == 1 || (lc >= 0 && lc < 128)) {
                int pos = (((lc >> 3) ^ s) << 3) | (lc & 7);
                sm16[row * 128 + pos] = f2b(acc2[mf][nf][r]);
              }
            }
          }
      }
      __syncthreads();
#pragma unroll
      for (int i = 0; i < 2; ++i) {
        int t = tid + i * 512;
        int row = t >> 4, cc = t & 15;
        int oc = cc ^ (row & 7);
        uint4 v = *(const uint4*)(&sm16[row * 128 + cc * 8]);
        *(uint4*)(&Out[((size_t)e * CAP + rb + row) * Os + Ocol + q * 128 + oc * 8]) = v;
      }
    }
  } else {
    // ---- f-chain: h2 to LDS (padded) + fw3 staged to LDS, 256->12 head ----
    __syncthreads();
    constexpr int H2S = 264;
    float* wsh = (float*)(&smP[64 * H2S]);
#pragma unroll
    for (int mf = 0; mf < 4; ++mf)
#pragma unroll
      for (int r = 0; r < 4; ++r) {
        int row = mf * 16 + g * 4 + r;
#pragma unroll
        for (int nf = 0; nf < NF2; ++nf) {
          int col = wn * WC2 + nf * 16 + l15;
          smP[row * H2S + col] = f2b(acc2[mf][nf][r]);
        }
      }
    for (int i = tid; i < 256 * 12; i += 512) wsh[i] = fw3[(size_t)e * 256 * 12 + i];
    __syncthreads();
#pragma unroll
    for (int it = 0; it < 2; ++it) {
      int idx = tid + it * 512;
      if (idx < 768) {
        int row = idx / 12, j = idx - row * 12;
        int slot2 = rb + row;
        if (slot2 < count) {
          float a = fb3[e * 12 + j];
          for (int c = 0; c < 256; ++c)
            a += b2f(smP[row * H2S + c]) * wsh[c * 12 + j];
          int arow = perm[e * CAP + slot2];
          allout[((size_t)arow * 8 + e) * 12 + j] = a;
        }
      }
    }
  }
}

// merged s+v chains: block-specialized, one launch (fills each other's idle slots)
__launch_bounds__(512, 4)
__global__ void k_sv(const unsigned short* __restrict__ st_bf,
                     const unsigned short* __restrict__ vl_bf,
                     const int* __restrict__ perm, const int* __restrict__ cnt,
                     const unsigned short* __restrict__ wS1, const float* __restrict__ sb1,
                     const float* __restrict__ sg1, const float* __restrict__ sh1,
                     const unsigned short* __restrict__ wS2, const float* __restrict__ sb2,
                     const float* __restrict__ sg2, const float* __restrict__ sh2,
                     const unsigned short* __restrict__ wV1, const float* __restrict__ vb1,
                     const float* __restrict__ vg1, const float* __restrict__ vh1,
                     const unsigned short* __restrict__ wV2, const float* __restrict__ vb2,
                     const float* __restrict__ vg2, const float* __restrict__ vh2,
                     unsigned short* __restrict__ bufF) {
  __shared__ char lds[70144];
  int bid = blockIdx.x;
  if (bid < NBLKC) {
    chain_body<512, 512, 256, true, false>(bid, lds, vl_bf, 512, perm, cnt,
        wV1, vb1, vg1, vh1, wV2, vb2, vg2, vh2,
        bufF, 384, 128, nullptr, nullptr, nullptr);
  } else {
    chain_body<128, 256, 128, true, false>(bid - NBLKC, lds, st_bf, 128, perm, cnt,
        wS1, sb1, sg1, sh1, wS2, sb2, sg2, sh2,
        bufF, 384, 0, nullptr, nullptr, nullptr);
  }
}

__launch_bounds__(512, 4)
__global__ void k_chainF(const unsigned short* __restrict__ bufF,
                         const int* __restrict__ perm, const int* __restrict__ cnt,
                         const unsigned short* __restrict__ wF1, const float* __restrict__ fb1,
                         const float* __restrict__ fg1, const float* __restrict__ fh1,
                         const unsigned short* __restrict__ wF2, const float* __restrict__ fb2,
                         const float* __restrict__ fg2, const float* __restrict__ fh2,
                         const float* __restrict__ fw3, const float* __restrict__ fb3,
                         float* __restrict__ allout) {
  __shared__ char lds[70144];
  chain_body<384, 512, 256, false, true>(blockIdx.x, lds, bufF, 384, perm, cnt,
      wF1, fb1, fg1, fh1, wF2, fb2, fg2, fh2,
      nullptr, 0, 0, fw3, fb3, allout);
}

// ------- mix: weighted sum of the two selected expert outputs -------
__global__ void k_mix(const float* __restrict__ selbuf, const float* __restrict__ allout,
                      float* __restrict__ out) {
  int b = blockIdx.x * 256 + threadIdx.x;
  int i0 = (int)selbuf[(size_t)b * 4 + 0];
  int i1 = (int)selbuf[(size_t)b * 4 + 1];
  float w0 = selbuf[(size_t)b * 4 + 2];
  float w1 = selbuf[(size_t)b * 4 + 3];
  const float* a0 = allout + ((size_t)b * 8 + i0) * 12;
  const float* a1 = allout + ((size_t)b * 8 + i1) * 12;
#pragma unroll
  for (int j = 0; j < 12; ++j)
    out[(size_t)b * 12 + j] = w0 * a0[j] + w1 * a1[j];
}

// ---------------- host ----------------

extern "C" void kernel_launch(void* const* d_in, const int* in_sizes, int n_in,
                              void* d_out, int out_size, void* d_ws, size_t ws_size,
                              hipStream_t stream) {
  const float* state = (const float*)d_in[0];
  const float* vlm   = (const float*)d_in[1];
  const float* sw1 = (const float*)d_in[2];  const float* sb1 = (const float*)d_in[3];
  const float* sg1 = (const float*)d_in[4];  const float* sh1 = (const float*)d_in[5];
  const float* sw2 = (const float*)d_in[6];  const float* sb2 = (const float*)d_in[7];
  const float* sg2 = (const float*)d_in[8];  const float* sh2 = (const float*)d_in[9];
  const float* vw1 = (const float*)d_in[10]; const float* vb1 = (const float*)d_in[11];
  const float* vg1 = (const float*)d_in[12]; const float* vh1 = (const float*)d_in[13];
  const float* vw2 = (const float*)d_in[14]; const float* vb2 = (const float*)d_in[15];
  const float* vg2 = (const float*)d_in[16]; const float* vh2 = (const float*)d_in[17];
  const float* fw1 = (const float*)d_in[18]; const float* fb1 = (const float*)d_in[19];
  const float* fg1 = (const float*)d_in[20]; const float* fh1 = (const float*)d_in[21];
  const float* fw2 = (const float*)d_in[22]; const float* fb2 = (const float*)d_in[23];
  const float* fg2 = (const float*)d_in[24]; const float* fh2 = (const float*)d_in[25];
  const float* fw3 = (const float*)d_in[26]; const float* fb3 = (const float*)d_in[27];
  const float* gw1 = (const float*)d_in[28]; const float* gb1 = (const float*)d_in[29];
  const float* gw2 = (const float*)d_in[30]; const float* gb2 = (const float*)d_in[31];
  const float* gw3 = (const float*)d_in[32]; const float* gb3 = (const float*)d_in[33];

  // ---- workspace (~165 MB; gh2 eliminated) ----
  char* ws = (char*)d_ws;
  size_t off = 0;
  auto alloc = [&](size_t bytes) -> char* {
    char* p = ws + off;
    off = (off + bytes + 255) & ~(size_t)255;
    return p;
  };
  unsigned short* st_bf = (unsigned short*)alloc((size_t)BROWS * 128 * 2);
  unsigned short* vl_bf = (unsigned short*)alloc((size_t)BROWS * 512 * 2);
  unsigned short* bufF  = (unsigned short*)alloc((size_t)NEXP * CAP * 384 * 2);
  float* allout = (float*)alloc((size_t)BROWS * 8 * 12 * 4);
  float* gh1    = (float*)alloc((size_t)BROWS * 256 * 4);
  float* selbuf = (float*)alloc((size_t)BROWS * 4 * 4);
  int*   perm   = (int*)alloc((size_t)NEXP * CAP * 4);
  int*   bcnt   = (int*)alloc(512 * 8 * 4);
  int*   bbase  = (int*)alloc(512 * 8 * 4);
  char*  cntaux = alloc(256);  // cnt: 8 ints at +0, aux: 8 floats at +64
  int*   cnt = (int*)cntaux;
  float* aux = (float*)(cntaux + 64);
  unsigned short* wt_s1 = (unsigned short*)alloc((size_t)8 * 256 * 128 * 2);
  unsigned short* wt_s2 = (unsigned short*)alloc((size_t)8 * 128 * 256 * 2);
  unsigned short* wt_v1 = (unsigned short*)alloc((size_t)8 * 512 * 512 * 2);
  unsigned short* wt_v2 = (unsigned short*)alloc((size_t)8 * 256 * 512 * 2);
  unsigned short* wt_f1 = (unsigned short*)alloc((size_t)8 * 512 * 384 * 2);
  unsigned short* wt_f2 = (unsigned short*)alloc((size_t)8 * 256 * 512 * 2);
  (void)ws_size; (void)in_sizes; (void)n_in; (void)out_size;

  float* outf = (float*)d_out;

  // front: gate1 GEMM + weight transposes + input converts, one launch (round-19)
  const int NBCV = (BROWS * 128) / 256 + (BROWS * 512) / 256;
  k_front<<<512 + 6144 + NBCV, 256, 0, stream>>>(
      state, vlm, st_bf, vl_bf, (int*)cntaux, gw1, gb1, gh1,
      sw1, wt_s1, sw2, wt_s2, vw1, wt_v1, vw2, wt_v2, fw1, wt_f1, fw2, wt_f2);

  // merged gate tail: gate2 GEMM + logits/top2/ballots in one kernel
  k_gtail<<<256, 256, 0, stream>>>(gh1, gw2, gb2, gw3, gb3, outf, aux, bcnt, selbuf);
  k_scanaux<<<1, 64, 0, stream>>>(bcnt, bbase, cnt, aux, outf);
  k_fill<<<512, 64, 0, stream>>>(selbuf, bbase, perm);

  // s+v chains merged (block-specialized) then f-chain
  k_sv<<<2 * NBLKC, 512, 0, stream>>>(st_bf, vl_bf, perm, cnt,
      wt_s1, sb1, sg1, sh1, wt_s2, sb2, sg2, sh2,
      wt_v1, vb1, vg1, vh1, wt_v2, vb2, vg2, vh2, bufF);
  k_chainF<<<NBLKC, 512, 0, stream>>>(bufF, perm, cnt,
      wt_f1, fb1, fg1, fh1, wt_f2, fb2, fg2, fh2, fw3, fb3, allout);

  k_mix<<<BROWS / 256, 256, 0, stream>>>(selbuf, allout, outf);
}